// Round 1
// baseline (275.244 us; speedup 1.0000x reference)
//
#include <hip/hip_runtime.h>

// ApplyPolicyMap: out[b, j] = inputs_flat[b, idx[j]] where idx[j] is the row
// of the single 1.0 in column j of the fixed 0/1 selection matrix pmap.
// The reference matmul [8192,5120] x [5120,1858] collapses to a gather.

#define C_IN    5120
#define N_MOVES 1858

// ---------------------------------------------------------------------------
// Kernel 1: recover idx[1858] from the dense pmap every call (d_ws is
// re-poisoned to 0xAA before each timed launch, so no caching is possible).
// pmap is [C_IN, N_MOVES] row-major; linear = r*N_MOVES + j.
// Exactly one nonzero per column -> non-atomic scatter write is race-free.
// ---------------------------------------------------------------------------
__global__ __launch_bounds__(256) void build_index_kernel(
        const float* __restrict__ pmap, int* __restrict__ idx) {
    const int total4 = (C_IN * N_MOVES) / 4;   // 5120*1858 divisible by 4
    const float4* __restrict__ p4 = (const float4*)pmap;
    int tid    = blockIdx.x * blockDim.x + threadIdx.x;
    int stride = gridDim.x * blockDim.x;
    for (int i = tid; i < total4; i += stride) {
        float4 v = p4[i];
        int base = i * 4;
        if (v.x != 0.0f) { int lin = base + 0; idx[lin % N_MOVES] = lin / N_MOVES; }
        if (v.y != 0.0f) { int lin = base + 1; idx[lin % N_MOVES] = lin / N_MOVES; }
        if (v.z != 0.0f) { int lin = base + 2; idx[lin % N_MOVES] = lin / N_MOVES; }
        if (v.w != 0.0f) { int lin = base + 3; idx[lin % N_MOVES] = lin / N_MOVES; }
    }
}

// ---------------------------------------------------------------------------
// Kernel 2: one block per batch row. Stage the 20 KB input row into LDS with
// coalesced float4 loads (the 1858 gathered positions touch essentially every
// 128B line of the row, so the full-row read is the HBM floor anyway), then
// gather from LDS and store coalesced.
// LDS = 20 KB -> 8 blocks/CU possible; wave cap (4 waves/block, 32/CU) also 8.
// ---------------------------------------------------------------------------
__global__ __launch_bounds__(256) void gather_policy_kernel(
        const float* __restrict__ in, const int* __restrict__ idx,
        float* __restrict__ out) {
    __shared__ float row[C_IN];
    const int b = blockIdx.x;

    const float4* __restrict__ src = (const float4*)(in + (size_t)b * C_IN);
    float4* dst4 = (float4*)row;
    #pragma unroll
    for (int i = threadIdx.x; i < C_IN / 4; i += 256) {
        dst4[i] = src[i];
    }
    __syncthreads();

    float* __restrict__ orow = out + (size_t)b * N_MOVES;
    for (int j = threadIdx.x; j < N_MOVES; j += 256) {
        orow[j] = row[idx[j]];      // idx[] is L1/L2-hot after the first blocks
    }
}

extern "C" void kernel_launch(void* const* d_in, const int* in_sizes, int n_in,
                              void* d_out, int out_size, void* d_ws, size_t ws_size,
                              hipStream_t stream) {
    const float* inputs = (const float*)d_in[0];   // [B, 80, 8, 8] fp32
    const float* pmap   = (const float*)d_in[1];   // [5120, 1858] fp32
    float*       out    = (float*)d_out;           // [B, 1858] fp32
    int*         idx    = (int*)d_ws;              // 1858 ints of scratch

    const int B = in_sizes[0] / C_IN;              // 8192

    // Build the column->row index map (reads 38 MB of pmap).
    build_index_kernel<<<2048, 256, 0, stream>>>(pmap, idx);

    // Gather: one block per batch row.
    gather_policy_kernel<<<B, 256, 0, stream>>>(inputs, idx, out);
}

// Round 3
// 255.254 us; speedup vs baseline: 1.0783x; 1.0783x over previous
//
#include <hip/hip_runtime.h>

// ApplyPolicyMap: out[b, j] = inputs_flat[b, idx[j]] where idx[j] is the row
// of the single 1.0 in column j of the fixed 0/1 selection matrix pmap.
// The reference matmul [8192,5120] x [5120,1858] collapses to a gather.
//
// Traffic floor per call: 38 MB (pmap scan, idx rebuild — d_ws is re-poisoned
// every call) + 168 MB (inputs) + 61 MB (out) ~= 267 MB ~= 42 us @ 6.3 TB/s.

#define C_IN    5120
#define N_MOVES 1858

// Native clang vectors: __builtin_nontemporal_* requires real vector types,
// not HIP_vector_type structs.
typedef float vf4 __attribute__((ext_vector_type(4)));
typedef float vf2 __attribute__((ext_vector_type(2)));

// ---------------------------------------------------------------------------
// Kernel 1: recover idx[1858] from dense pmap. Exactly one nonzero per column
// -> non-atomic scatter is race-free. 38 MB streamed read, nontemporal.
// ---------------------------------------------------------------------------
__global__ __launch_bounds__(256) void build_index_kernel(
        const float* __restrict__ pmap, int* __restrict__ idx) {
    const int total4 = (C_IN * N_MOVES) / 4;   // divisible by 4
    const vf4* __restrict__ p4 = (const vf4*)pmap;
    int tid    = blockIdx.x * blockDim.x + threadIdx.x;
    int stride = gridDim.x * blockDim.x;
    for (int i = tid; i < total4; i += stride) {
        vf4 v = __builtin_nontemporal_load(&p4[i]);
        int base = i * 4;
        if (v.x != 0.0f) { int lin = base + 0; idx[lin % N_MOVES] = lin / N_MOVES; }
        if (v.y != 0.0f) { int lin = base + 1; idx[lin % N_MOVES] = lin / N_MOVES; }
        if (v.z != 0.0f) { int lin = base + 2; idx[lin % N_MOVES] = lin / N_MOVES; }
        if (v.w != 0.0f) { int lin = base + 3; idx[lin % N_MOVES] = lin / N_MOVES; }
    }
}

// ---------------------------------------------------------------------------
// Kernel 2: one block (256 thr) per batch row.
//  - hoist idx[] loads into registers BEFORE the staging barrier (overlap the
//    ~200cy L2-hot latency with the row-staging VMEM)
//  - stage the 20 KB row into LDS via nontemporal float4 loads (coalesced)
//  - gather from LDS, store coalesced as float2 (1858 = 929 x float2, row
//    byte offset b*7432 is 8B-aligned)
// LDS 20 KB -> 8 blocks/CU; 4 waves/block -> full 32 waves/CU occupancy.
// ---------------------------------------------------------------------------
__global__ __launch_bounds__(256) void gather_policy_kernel(
        const float* __restrict__ in, const int* __restrict__ idx,
        float* __restrict__ out) {
    __shared__ float row[C_IN];
    const int b   = blockIdx.x;
    const int tid = threadIdx.x;

    // --- issue row-staging loads (global -> reg), 5 x float4 per thread ---
    const vf4* __restrict__ src = (const vf4*)(in + (size_t)b * C_IN);
    vf4 stage[5];
    #pragma unroll
    for (int k = 0; k < 5; ++k)
        stage[k] = __builtin_nontemporal_load(&src[tid + k * 256]);

    // --- overlap: load this thread's gather indices (L2-hot, 7.4 KB) ---
    // 929 float2 outputs, 256 threads -> up to 4 float2 (8 idx) per thread.
    int my_idx[8];
    #pragma unroll
    for (int k = 0; k < 4; ++k) {
        int j2 = tid + k * 256;          // float2 element index
        if (j2 < N_MOVES / 2) {
            my_idx[2 * k]     = idx[2 * j2];
            my_idx[2 * k + 1] = idx[2 * j2 + 1];
        }
    }

    // --- regs -> LDS ---
    vf4* dst4 = (vf4*)row;
    #pragma unroll
    for (int k = 0; k < 5; ++k)
        dst4[tid + k * 256] = stage[k];
    __syncthreads();

    // --- gather + coalesced float2 stores ---
    vf2* __restrict__ orow2 = (vf2*)(out + (size_t)b * N_MOVES);
    #pragma unroll
    for (int k = 0; k < 4; ++k) {
        int j2 = tid + k * 256;
        if (j2 < N_MOVES / 2) {
            vf2 v;
            v.x = row[my_idx[2 * k]];
            v.y = row[my_idx[2 * k + 1]];
            __builtin_nontemporal_store(v, &orow2[j2]);
        }
    }
}

extern "C" void kernel_launch(void* const* d_in, const int* in_sizes, int n_in,
                              void* d_out, int out_size, void* d_ws, size_t ws_size,
                              hipStream_t stream) {
    const float* inputs = (const float*)d_in[0];   // [B, 80, 8, 8] fp32
    const float* pmap   = (const float*)d_in[1];   // [5120, 1858] fp32
    float*       out    = (float*)d_out;           // [B, 1858] fp32
    int*         idx    = (int*)d_ws;              // 1858 ints of scratch

    const int B = in_sizes[0] / C_IN;              // 8192

    build_index_kernel<<<2048, 256, 0, stream>>>(pmap, idx);
    gather_policy_kernel<<<B, 256, 0, stream>>>(inputs, idx, out);
}